// Round 1
// baseline (401.299 us; speedup 1.0000x reference)
//
#include <hip/hip_runtime.h>
#include <hip/hip_bf16.h>

#define B_ 64
#define C_ 128
#define N_ 8192
#define P_ 2048
#define K_ 7

// ---------------------------------------------------------------------------
// Meta layout in d_ws: per p, 8 ints: idx0..idx6 (invalid slots -> 0),
// word7 = mask bits (low 7 bits). 2048 * 32 B = 64 KB.
// Shared by all 8192 (b,c) rows -> stays L2-resident.
// ---------------------------------------------------------------------------
__global__ __launch_bounds__(256) void build_meta_kernel(
    const int* __restrict__ idx, const unsigned* __restrict__ mask_raw,
    int* __restrict__ meta) {
  int p = blockIdx.x * 256 + threadIdx.x;
  if (p >= P_) return;
  // Sniff mask dtype from first word. lengths >= 3 so mask[0][0..2] are true.
  //   int32 layout : word0 == 1
  //   float32      : word0 == 0x3F800000 (1.0f)
  //   byte (bool)  : word0 == 0x00010101 or 0x01010101
  unsigned w0 = mask_raw[0];
  int bits = 0;
  if (w0 == 1u) {
    const int* m = (const int*)mask_raw;
#pragma unroll
    for (int k = 0; k < K_; ++k) bits |= (int)(m[p * K_ + k] != 0) << k;
  } else if (w0 == 0x3F800000u) {
    const float* m = (const float*)mask_raw;
#pragma unroll
    for (int k = 0; k < K_; ++k) bits |= (int)(m[p * K_ + k] != 0.0f) << k;
  } else {
    const unsigned char* m = (const unsigned char*)mask_raw;
#pragma unroll
    for (int k = 0; k < K_; ++k) bits |= (int)(m[p * K_ + k] != 0) << k;
  }
#pragma unroll
  for (int k = 0; k < K_; ++k)
    meta[p * 8 + k] = ((bits >> k) & 1) ? idx[p * K_ + k] : 0;
  meta[p * 8 + 7] = bits;
}

// ---------------------------------------------------------------------------
// Main kernel: one block per (b,c) row. Stage the 32 KB x-row in LDS with
// coalesced float4 loads, then each thread produces 8 of the 2048 outputs
// via LDS gathers. Output writes are fully coalesced.
// ---------------------------------------------------------------------------
__global__ __launch_bounds__(256, 4) void pool_kernel(
    const float* __restrict__ x, const int4* __restrict__ meta,
    float* __restrict__ out) {
  __shared__ float row[N_];  // 32 KB -> up to 5 blocks/CU by LDS
  const int bc = blockIdx.x;
  const float4* __restrict__ x4 = (const float4*)(x + (size_t)bc * N_);
  float4* row4 = (float4*)row;
#pragma unroll
  for (int i = 0; i < N_ / 4 / 256; ++i) {
    int t = threadIdx.x + i * 256;
    row4[t] = x4[t];
  }
  __syncthreads();
  float* __restrict__ orow = out + (size_t)bc * P_;
#pragma unroll
  for (int j = 0; j < P_ / 256; ++j) {
    int p = threadIdx.x + j * 256;
    int4 m0 = meta[2 * p];
    int4 m1 = meta[2 * p + 1];
    int bits = m1.w;
    float inv = 1.0f / (float)__popc(bits & 0x7f);
    float s = 0.0f;
    s += ((bits >> 0) & 1) ? row[m0.x] : 0.0f;
    s += ((bits >> 1) & 1) ? row[m0.y] : 0.0f;
    s += ((bits >> 2) & 1) ? row[m0.z] : 0.0f;
    s += ((bits >> 3) & 1) ? row[m0.w] : 0.0f;
    s += ((bits >> 4) & 1) ? row[m1.x] : 0.0f;
    s += ((bits >> 5) & 1) ? row[m1.y] : 0.0f;
    s += ((bits >> 6) & 1) ? row[m1.z] : 0.0f;
    orow[p] = s * inv;
  }
}

// ---------------------------------------------------------------------------
// Fallback (only if ws_size < 64 KB): compute mask bits inline per thread.
// ---------------------------------------------------------------------------
__global__ __launch_bounds__(256, 4) void pool_kernel_direct(
    const float* __restrict__ x, const int* __restrict__ idx,
    const unsigned* __restrict__ mask_raw, float* __restrict__ out) {
  __shared__ float row[N_];
  const int bc = blockIdx.x;
  const float4* __restrict__ x4 = (const float4*)(x + (size_t)bc * N_);
  float4* row4 = (float4*)row;
#pragma unroll
  for (int i = 0; i < N_ / 4 / 256; ++i) {
    int t = threadIdx.x + i * 256;
    row4[t] = x4[t];
  }
  __syncthreads();
  unsigned w0 = mask_raw[0];
  float* __restrict__ orow = out + (size_t)bc * P_;
  for (int j = 0; j < P_ / 256; ++j) {
    int p = threadIdx.x + j * 256;
    int bits = 0;
    if (w0 == 1u) {
      const int* m = (const int*)mask_raw;
#pragma unroll
      for (int k = 0; k < K_; ++k) bits |= (int)(m[p * K_ + k] != 0) << k;
    } else if (w0 == 0x3F800000u) {
      const float* m = (const float*)mask_raw;
#pragma unroll
      for (int k = 0; k < K_; ++k) bits |= (int)(m[p * K_ + k] != 0.0f) << k;
    } else {
      const unsigned char* m = (const unsigned char*)mask_raw;
#pragma unroll
      for (int k = 0; k < K_; ++k) bits |= (int)(m[p * K_ + k] != 0) << k;
    }
    float s = 0.0f;
    float inv = 1.0f / (float)__popc(bits & 0x7f);
#pragma unroll
    for (int k = 0; k < K_; ++k) {
      int id = ((bits >> k) & 1) ? idx[p * K_ + k] : 0;
      float v = row[id];
      s += ((bits >> k) & 1) ? v : 0.0f;
    }
    orow[p] = s * inv;
  }
}

extern "C" void kernel_launch(void* const* d_in, const int* in_sizes, int n_in,
                              void* d_out, int out_size, void* d_ws, size_t ws_size,
                              hipStream_t stream) {
  const float* x = (const float*)d_in[0];
  const int* idx = (const int*)d_in[1];
  const unsigned* mask = (const unsigned*)d_in[2];
  float* out = (float*)d_out;

  if (ws_size >= (size_t)P_ * 8 * sizeof(int)) {
    int* meta = (int*)d_ws;
    build_meta_kernel<<<(P_ + 255) / 256, 256, 0, stream>>>(idx, mask, meta);
    pool_kernel<<<B_ * C_, 256, 0, stream>>>(x, (const int4*)meta, out);
  } else {
    pool_kernel_direct<<<B_ * C_, 256, 0, stream>>>(x, idx, mask, out);
  }
}

// Round 6
// 390.666 us; speedup vs baseline: 1.0272x; 1.0272x over previous
//
#include <hip/hip_runtime.h>
#include <hip/hip_bf16.h>

#define B_ 64
#define C_ 128
#define N_ 8192
#define P_ 2048
#define K_ 7

typedef float fx4 __attribute__((ext_vector_type(4)));  // native vector: legal
                                                        // for nontemporal builtins

// ---------------------------------------------------------------------------
// Meta layout in d_ws: per p, 8 ints: idx0..idx6 (invalid slots -> 0),
// word7 = mask bits (low 7 bits). 2048 * 32 B = 64 KB.
// Shared by all 8192 (b,c) rows -> stays L2-resident per XCD.
// ---------------------------------------------------------------------------
__global__ __launch_bounds__(256) void build_meta_kernel(
    const int* __restrict__ idx, const unsigned* __restrict__ mask_raw,
    int* __restrict__ meta) {
  int p = blockIdx.x * 256 + threadIdx.x;
  if (p >= P_) return;
  // Sniff mask dtype from first word. lengths >= 3 so mask[0][0..2] are true.
  //   int32 layout : word0 == 1
  //   float32      : word0 == 0x3F800000 (1.0f)
  //   byte (bool)  : word0 == 0x00010101 or 0x01010101
  unsigned w0 = mask_raw[0];
  int bits = 0;
  if (w0 == 1u) {
    const int* m = (const int*)mask_raw;
#pragma unroll
    for (int k = 0; k < K_; ++k) bits |= (int)(m[p * K_ + k] != 0) << k;
  } else if (w0 == 0x3F800000u) {
    const float* m = (const float*)mask_raw;
#pragma unroll
    for (int k = 0; k < K_; ++k) bits |= (int)(m[p * K_ + k] != 0.0f) << k;
  } else {
    const unsigned char* m = (const unsigned char*)mask_raw;
#pragma unroll
    for (int k = 0; k < K_; ++k) bits |= (int)(m[p * K_ + k] != 0) << k;
  }
#pragma unroll
  for (int k = 0; k < K_; ++k)
    meta[p * 8 + k] = ((bits >> k) & 1) ? idx[p * K_ + k] : 0;
  meta[p * 8 + 7] = bits;
}

// ---------------------------------------------------------------------------
// Main kernel: one block per (b,c) row. 512 threads -> 4 blocks/CU = 32
// waves/CU (HW cap) with 4x32KB = 128 KB LDS. Stage the 32 KB x-row in LDS
// with coalesced nontemporal float4 loads (x is stream-once; keep it out of
// L2 so the hot 64 KB meta stays resident), then each thread produces 4 of
// the 2048 outputs via LDS gathers. Output stores nontemporal + coalesced.
// ---------------------------------------------------------------------------
__global__ __launch_bounds__(512) void pool_kernel(
    const float* __restrict__ x, const int4* __restrict__ meta,
    float* __restrict__ out) {
  __shared__ float row[N_];  // 32 KB
  const int bc = blockIdx.x;
  const fx4* __restrict__ x4 = (const fx4*)(x + (size_t)bc * N_);
  fx4* row4 = (fx4*)row;
#pragma unroll
  for (int i = 0; i < N_ / 4 / 512; ++i) {  // 4 iters
    int t = threadIdx.x + i * 512;
    row4[t] = __builtin_nontemporal_load(&x4[t]);
  }
  __syncthreads();
  float* __restrict__ orow = out + (size_t)bc * P_;
#pragma unroll
  for (int j = 0; j < P_ / 512; ++j) {  // 4 iters
    int p = threadIdx.x + j * 512;
    int4 m0 = meta[2 * p];
    int4 m1 = meta[2 * p + 1];
    int bits = m1.w;
    float inv = 1.0f / (float)__popc(bits & 0x7f);
    float s = 0.0f;
    s += ((bits >> 0) & 1) ? row[m0.x] : 0.0f;
    s += ((bits >> 1) & 1) ? row[m0.y] : 0.0f;
    s += ((bits >> 2) & 1) ? row[m0.z] : 0.0f;
    s += ((bits >> 3) & 1) ? row[m0.w] : 0.0f;
    s += ((bits >> 4) & 1) ? row[m1.x] : 0.0f;
    s += ((bits >> 5) & 1) ? row[m1.y] : 0.0f;
    s += ((bits >> 6) & 1) ? row[m1.z] : 0.0f;
    __builtin_nontemporal_store(s * inv, &orow[p]);
  }
}

// ---------------------------------------------------------------------------
// Fallback (only if ws_size < 64 KB): compute mask bits inline per thread.
// ---------------------------------------------------------------------------
__global__ __launch_bounds__(256) void pool_kernel_direct(
    const float* __restrict__ x, const int* __restrict__ idx,
    const unsigned* __restrict__ mask_raw, float* __restrict__ out) {
  __shared__ float row[N_];
  const int bc = blockIdx.x;
  const float4* __restrict__ x4 = (const float4*)(x + (size_t)bc * N_);
  float4* row4 = (float4*)row;
#pragma unroll
  for (int i = 0; i < N_ / 4 / 256; ++i) {
    int t = threadIdx.x + i * 256;
    row4[t] = x4[t];
  }
  __syncthreads();
  unsigned w0 = mask_raw[0];
  float* __restrict__ orow = out + (size_t)bc * P_;
  for (int j = 0; j < P_ / 256; ++j) {
    int p = threadIdx.x + j * 256;
    int bits = 0;
    if (w0 == 1u) {
      const int* m = (const int*)mask_raw;
#pragma unroll
      for (int k = 0; k < K_; ++k) bits |= (int)(m[p * K_ + k] != 0) << k;
    } else if (w0 == 0x3F800000u) {
      const float* m = (const float*)mask_raw;
#pragma unroll
      for (int k = 0; k < K_; ++k) bits |= (int)(m[p * K_ + k] != 0.0f) << k;
    } else {
      const unsigned char* m = (const unsigned char*)mask_raw;
#pragma unroll
      for (int k = 0; k < K_; ++k) bits |= (int)(m[p * K_ + k] != 0) << k;
    }
    float s = 0.0f;
    float inv = 1.0f / (float)__popc(bits & 0x7f);
#pragma unroll
    for (int k = 0; k < K_; ++k) {
      int id = ((bits >> k) & 1) ? idx[p * K_ + k] : 0;
      float v = row[id];
      s += ((bits >> k) & 1) ? v : 0.0f;
    }
    orow[p] = s * inv;
  }
}

extern "C" void kernel_launch(void* const* d_in, const int* in_sizes, int n_in,
                              void* d_out, int out_size, void* d_ws, size_t ws_size,
                              hipStream_t stream) {
  const float* x = (const float*)d_in[0];
  const int* idx = (const int*)d_in[1];
  const unsigned* mask = (const unsigned*)d_in[2];
  float* out = (float*)d_out;

  if (ws_size >= (size_t)P_ * 8 * sizeof(int)) {
    int* meta = (int*)d_ws;
    build_meta_kernel<<<(P_ + 255) / 256, 256, 0, stream>>>(idx, mask, meta);
    pool_kernel<<<B_ * C_, 512, 0, stream>>>(x, (const int4*)meta, out);
  } else {
    pool_kernel_direct<<<B_ * C_, 256, 0, stream>>>(x, idx, mask, out);
  }
}